// Round 6
// baseline (496.347 us; speedup 1.0000x reference)
//
#include <hip/hip_runtime.h>
#include <hip/hip_bf16.h>

typedef __attribute__((ext_vector_type(8))) short bf16x8;
typedef __attribute__((ext_vector_type(4))) float f32x4;

constexpr int D = 128;
constexpr int R = 8;
constexpr float BN_EPS = 1e-5f;

__device__ __forceinline__ unsigned short f2bf(float x) {
  __hip_bfloat16 b = __float2bfloat16(x);
  union { __hip_bfloat16 b; unsigned short u; } c; c.b = b; return c.u;
}
__device__ __forceinline__ float bf2f(unsigned short u) {
  union { float f; unsigned int i; } c; c.i = ((unsigned int)u) << 16; return c.f;
}

// ---------------------------------------------------------------------------
// Counting sort of edges by key = dst*8 + rel (structure shared by both layers)
// ---------------------------------------------------------------------------
__global__ __launch_bounds__(256) void hist_k(const int* __restrict__ ei,
                                              const int* __restrict__ et,
                                              int* __restrict__ cnt, int E) {
  int e = blockIdx.x * 256 + threadIdx.x;
  if (e >= E) return;
  atomicAdd(&cnt[ei[E + e] * 8 + et[e]], 1);
}

__global__ __launch_bounds__(256) void scan_partial_k(const int* __restrict__ cnt,
                                                      int* __restrict__ offs,
                                                      int* __restrict__ bsum, int NK) {
  __shared__ int s[256];
  int tid = threadIdx.x;
  int base = blockIdx.x * 4096 + tid * 16;
  int loc[16];
  int sum = 0;
  #pragma unroll
  for (int i = 0; i < 16; ++i) {
    int idx = base + i;
    int v = (idx < NK) ? cnt[idx] : 0;
    loc[i] = sum; sum += v;
  }
  s[tid] = sum;
  __syncthreads();
  if (tid == 0) {
    int run = 0;
    for (int i = 0; i < 256; ++i) { int t = s[i]; s[i] = run; run += t; }
    bsum[blockIdx.x] = run;
  }
  __syncthreads();
  int off = s[tid];
  #pragma unroll
  for (int i = 0; i < 16; ++i) {
    int idx = base + i;
    if (idx < NK) offs[idx] = off + loc[i];
  }
}

__global__ void scan_bsums_k(int* __restrict__ bsum, int nb) {
  if (threadIdx.x == 0 && blockIdx.x == 0) {
    int run = 0;
    for (int b = 0; b < nb; ++b) { int t = bsum[b]; bsum[b] = run; run += t; }
  }
}

__global__ __launch_bounds__(256) void scan_addback_k(int* __restrict__ offs,
                                                      const int* __restrict__ bsum,
                                                      int NK, int E) {
  int idx = blockIdx.x * 256 + threadIdx.x;
  if (idx < NK) offs[idx] += bsum[idx >> 12];
  if (idx == 0) offs[NK] = E;
}

// place: also pre-gather src so agg has no dependent index chain
__global__ __launch_bounds__(256) void place_k(const int* __restrict__ ei,
                                               const int* __restrict__ et,
                                               const int* __restrict__ offs,
                                               int* __restrict__ cnt,
                                               int2* __restrict__ pairs, int E) {
  int e = blockIdx.x * 256 + threadIdx.x;
  if (e >= E) return;
  int key = ei[E + e] * 8 + et[e];
  int pos = offs[key] + atomicAdd(&cnt[key], 1);
  pairs[pos] = make_int2(e, ei[e]);
}

// ---------------------------------------------------------------------------
// Segment mean: each 32-lane group owns FOUR consecutive (dst,rel) segments.
// XMODE 0 (layer 0): gather xe fp32 by edge id; ALSO write xep[pos] (bf16,
//   message-sorted order) so layer 1 streams it.
// XMODE 1 (layer 1): read xep positionally (contiguous, half bytes, no shfl
//   for the edge id).
// Output: Mb [NK][128] bf16, k-swizzled per 32-channel tile for MFMA frags.
// ---------------------------------------------------------------------------
template <int XMODE>
__device__ __forceinline__ void edge_proc(float4& acc, int pos, int e, int s, int c,
                                          const float* __restrict__ h,
                                          const float* __restrict__ xe,
                                          unsigned short* __restrict__ xep) {
  float4 xv;
  if (XMODE == 0) {
    xv = ((const float4*)xe)[(size_t)e * 32 + c];
    ushort4 u;
    u.x = f2bf(xv.x); u.y = f2bf(xv.y); u.z = f2bf(xv.z); u.w = f2bf(xv.w);
    *(ushort4*)(xep + (size_t)pos * 128 + c * 4) = u;
  } else {
    ushort4 u = *(const ushort4*)(xep + (size_t)pos * 128 + c * 4);
    xv.x = bf2f(u.x); xv.y = bf2f(u.y); xv.z = bf2f(u.z); xv.w = bf2f(u.w);
  }
  float4 hv = ((const float4*)h)[(size_t)s * 32 + c];
  acc.x += fmaxf(xv.x + hv.x, 0.f);
  acc.y += fmaxf(xv.y + hv.y, 0.f);
  acc.z += fmaxf(xv.z + hv.z, 0.f);
  acc.w += fmaxf(xv.w + hv.w, 0.f);
}

template <int XMODE>
__global__ __launch_bounds__(256) void agg_k(const float* __restrict__ h,
                                             const float* __restrict__ xe,
                                             unsigned short* __restrict__ xep,
                                             const int2* __restrict__ pairs,
                                             const int* __restrict__ offs,
                                             unsigned short* __restrict__ Mb, int NK) {
  int grp = threadIdx.x >> 5;
  int s0 = (blockIdx.x * 8 + grp) * 4;
  if (s0 >= NK) return;
  int c = threadIdx.x & 31;

  int4 ov = *(const int4*)(offs + s0);   // s0 % 4 == 0 -> 16B aligned
  int o4 = offs[s0 + 4];
  int st[4] = {ov.x, ov.y, ov.z, ov.w};
  int en[4] = {ov.y, ov.z, ov.w, o4};

  // issue all 4 pairs loads up front (independent)
  int2 pr[4];
  #pragma unroll
  for (int j = 0; j < 4; ++j) {
    int m = en[j] - st[j];
    if (m > 0) pr[j] = pairs[st[j] + min(c, min(m, 32) - 1)];
  }

  float4 acc[4];
  #pragma unroll
  for (int j = 0; j < 4; ++j) acc[j] = make_float4(0.f, 0.f, 0.f, 0.f);

#define EP(j, i) edge_proc<XMODE>(acc[j], st[j] + (i), \
    (XMODE == 0) ? __shfl(pr[j].x, (i), 32) : 0, \
    __shfl(pr[j].y, (i), 32), c, h, xe, xep)

  #pragma unroll
  for (int j = 0; j < 4; ++j) {
    int m = en[j] - st[j];
    if (m > 0) {
      int mm = min(m, 32);
      EP(j, 0);
      if (mm >= 2) EP(j, 1);
      if (mm >= 3) EP(j, 2);
      if (mm >= 4) EP(j, 3);
      for (int i = 4; i < mm; ++i) EP(j, i);
      // rare: segments longer than 32
      for (int base = st[j] + 32; base < en[j]; base += 32) {
        int mm2 = min(32, en[j] - base);
        int2 pr2 = pairs[base + min(c, mm2 - 1)];
        for (int i = 0; i < mm2; ++i)
          edge_proc<XMODE>(acc[j], base + i,
                           (XMODE == 0) ? __shfl(pr2.x, i, 32) : 0,
                           __shfl(pr2.y, i, 32), c, h, xe, xep);
      }
    }
  }
#undef EP

  int pos = (c >> 3) * 32 + (c & 3) * 8 + ((c >> 2) & 1) * 4;
  #pragma unroll
  for (int j = 0; j < 4; ++j) {
    int len = en[j] - st[j];
    float inv = (len > 0) ? 1.0f / (float)len : 0.f;
    ushort4 u;
    u.x = f2bf(acc[j].x * inv); u.y = f2bf(acc[j].y * inv);
    u.z = f2bf(acc[j].z * inv); u.w = f2bf(acc[j].w * inv);
    *(ushort4*)(Mb + (size_t)(s0 + j) * 128 + pos) = u;
  }
}

// cast fp32 [N,128] -> bf16 swizzled [N,128]
__global__ __launch_bounds__(256) void cast_swz_k(const float* __restrict__ in,
                                                  unsigned short* __restrict__ outb, int n4) {
  int gi = blockIdx.x * 256 + threadIdx.x;
  if (gi >= n4) return;
  int n = gi >> 5, c = gi & 31;
  float4 v = ((const float4*)in)[gi];
  int pos = (c >> 3) * 32 + (c & 3) * 8 + ((c >> 2) & 1) * 4;
  ushort4 u;
  u.x = f2bf(v.x); u.y = f2bf(v.y); u.z = f2bf(v.z); u.w = f2bf(v.w);
  *(ushort4*)(outb + (size_t)n * 128 + pos) = u;
}

// W[1152,128] (weight_l | root_l) -> transposed [col][1152], k-swizzled, bf16
__global__ __launch_bounds__(256) void wcast_k(const float* __restrict__ W,
                                               const float* __restrict__ root,
                                               unsigned short* __restrict__ Whi) {
  int idx = blockIdx.x * 256 + threadIdx.x;   // 1152*128 = 147456
  if (idx >= 1152 * 128) return;
  int k = idx >> 7, col = idx & 127;
  float w = (k < 1024) ? W[idx] : root[idx - 1024 * 128];
  int kk = k & 31;
  int pos = (k & ~31) + ((kk & 15) >> 2) * 8 + (kk >> 4) * 4 + (kk & 3);
  Whi[col * 1152 + pos] = f2bf(w);
}

// ---------------------------------------------------------------------------
// MFMA GEMM with explicit register software-pipeline: next tile's 8 A-frags
// are loaded BEFORE the current tile's 16 MFMAs (guaranteed 8 loads in
// flight under compute). 256 thr = 4 waves, block = 128 rows, wave = 32 cols.
// Fused BN column sum/sumsq epilogue.
// ---------------------------------------------------------------------------
__global__ __launch_bounds__(256) void gemm_k(
    const unsigned short* __restrict__ Mb,   // [N,1024] swz
    const unsigned short* __restrict__ hb,   // [N,128] swz
    const unsigned short* __restrict__ Whi,  // [128 cols][1152] swz-k
    const float* __restrict__ bias,
    float* __restrict__ out,
    float* __restrict__ colstats, int N) {
  __shared__ float ldsS[128], ldsQ[128];
  const int tid = threadIdx.x;
  const int wv = tid >> 6, lane = tid & 63;
  const int lr = lane & 15, g = lane >> 4;
  const int r0 = blockIdx.x * 128;
  const int cf0 = wv * 2;

  int row[8];
  #pragma unroll
  for (int rf = 0; rf < 8; ++rf) row[rf] = min(r0 + rf * 16 + lr, N - 1);

  const unsigned short* pb0 = Whi + (size_t)(cf0 * 16 + lr) * 1152 + g * 8;
  const unsigned short* pb1 = pb0 + 16 * 1152;

  f32x4 acc[8][2];
  #pragma unroll
  for (int a = 0; a < 8; ++a)
    #pragma unroll
    for (int b = 0; b < 2; ++b) acc[a][b] = (f32x4){0.f, 0.f, 0.f, 0.f};

  auto aload = [&](int t, int rf) -> bf16x8 {
    if (t < 32)
      return *(const bf16x8*)(Mb + (size_t)row[rf] * 1024 + t * 32 + g * 8);
    return *(const bf16x8*)(hb + (size_t)row[rf] * 128 + (t - 32) * 32 + g * 8);
  };

  bf16x8 a_cur[8];
  #pragma unroll
  for (int rf = 0; rf < 8; ++rf) a_cur[rf] = aload(0, rf);

  #pragma unroll 2
  for (int t = 0; t < 36; ++t) {
    bf16x8 a_nxt[8];
    if (t < 35) {
      #pragma unroll
      for (int rf = 0; rf < 8; ++rf) a_nxt[rf] = aload(t + 1, rf);
    }
    bf16x8 b0 = *(const bf16x8*)(pb0 + t * 32);
    bf16x8 b1 = *(const bf16x8*)(pb1 + t * 32);
    #pragma unroll
    for (int rf = 0; rf < 8; ++rf) {
      acc[rf][0] = __builtin_amdgcn_mfma_f32_16x16x32_bf16(a_cur[rf], b0, acc[rf][0], 0, 0, 0);
      acc[rf][1] = __builtin_amdgcn_mfma_f32_16x16x32_bf16(a_cur[rf], b1, acc[rf][1], 0, 0, 0);
    }
    #pragma unroll
    for (int rf = 0; rf < 8; ++rf) a_cur[rf] = a_nxt[rf];
  }

  // epilogue: bias, store, BN column stats
  #pragma unroll
  for (int c = 0; c < 2; ++c) {
    int col = (cf0 + c) * 16 + lr;
    float bs = bias[col];
    float s = 0.f, q = 0.f;
    #pragma unroll
    for (int rf = 0; rf < 8; ++rf) {
      #pragma unroll
      for (int j = 0; j < 4; ++j) {
        int r = r0 + rf * 16 + g * 4 + j;
        if (r < N) {
          float v = acc[rf][c][j] + bs;
          out[(size_t)r * 128 + col] = v;
          s += v; q += v * v;
        }
      }
    }
    s += __shfl_xor(s, 16); s += __shfl_xor(s, 32);
    q += __shfl_xor(q, 16); q += __shfl_xor(q, 32);
    if (g == 0) { ldsS[col] = s; ldsQ[col] = q; }
  }
  __syncthreads();
  if (tid < 128) {
    atomicAdd(&colstats[tid], ldsS[tid]);
    atomicAdd(&colstats[128 + tid], ldsQ[tid]);
  }
}

// ---------------------------------------------------------------------------
// BN apply; optionally also emit bf16-swizzled copy for next layer's root term
// ---------------------------------------------------------------------------
__global__ __launch_bounds__(256) void bn_apply_k(
    const float* __restrict__ in, float* __restrict__ out,
    unsigned short* __restrict__ hbOut,
    const float* __restrict__ colstats,
    const float* __restrict__ gamma, const float* __restrict__ beta,
    int N, int doRelu) {
  int gi = blockIdx.x * 256 + threadIdx.x;
  if (gi >= N * 32) return;
  int n = gi >> 5, c = gi & 31;
  int c0 = c * 4;
  float invN = 1.0f / (float)N;
  float4 v = ((const float4*)in)[gi];
  float4 o;
  #pragma unroll
  for (int j = 0; j < 4; ++j) {
    int cc = c0 + j;
    float mu = colstats[cc] * invN;
    float var = colstats[128 + cc] * invN - mu * mu;
    float scale = rsqrtf(var + BN_EPS) * gamma[cc];
    float shift = beta[cc] - mu * scale;
    float x = (j == 0) ? v.x : (j == 1) ? v.y : (j == 2) ? v.z : v.w;
    float y = x * scale + shift;
    if (doRelu) y = fmaxf(y, 0.f);
    if (j == 0) o.x = y; else if (j == 1) o.y = y; else if (j == 2) o.z = y; else o.w = y;
  }
  ((float4*)out)[gi] = o;
  if (hbOut) {
    int pos = (c >> 3) * 32 + (c & 3) * 8 + ((c >> 2) & 1) * 4;
    ushort4 u;
    u.x = f2bf(o.x); u.y = f2bf(o.y); u.z = f2bf(o.z); u.w = f2bf(o.w);
    *(ushort4*)(hbOut + (size_t)n * 128 + pos) = u;
  }
}

extern "C" void kernel_launch(void* const* d_in, const int* in_sizes, int n_in,
                              void* d_out, int out_size, void* d_ws, size_t ws_size,
                              hipStream_t stream) {
  const float* x      = (const float*)d_in[0];
  const float* xe     = (const float*)d_in[1];
  const int*   ei     = (const int*)d_in[2];
  const int*   et     = (const int*)d_in[3];
  const float* weight = (const float*)d_in[4];
  const float* root   = (const float*)d_in[5];
  const float* bias   = (const float*)d_in[6];
  const float* gamma  = (const float*)d_in[7];
  const float* beta   = (const float*)d_in[8];
  float* out = (float*)d_out;

  const int N = in_sizes[0] / D;   // 50000
  const int E = in_sizes[3];       // 500000
  const int NK = N * R;            // 400000

  // workspace layout (256B-aligned chunks)
  char* w = (char*)d_ws;
  size_t off = 0;
  auto alloc = [&](size_t bytes) { char* p = w + off; off = (off + bytes + 255) & ~(size_t)255; return p; };
  unsigned short* Mb   = (unsigned short*)alloc((size_t)NK * 128 * 2);
  unsigned short* xep  = (unsigned short*)alloc((size_t)E * 128 * 2);
  unsigned short* hb   = (unsigned short*)alloc((size_t)N * 128 * 2);
  float*          h1   = (float*)alloc((size_t)N * 128 * 4);
  unsigned short* Whi  = (unsigned short*)alloc(1152 * 128 * 2);
  int*            offs = (int*)alloc((size_t)(NK + 1) * 4);
  int*            cnt  = (int*)alloc((size_t)NK * 4);
  int2*           pairs= (int2*)alloc((size_t)E * 8);
  int*            bsum = (int*)alloc(512 * 4);
  float*          cst  = (float*)alloc(256 * 4);

  const int NB = (NK + 4095) / 4096;

  // --- counting sort (edge structure; shared by both layers) ---
  hipMemsetAsync(cnt, 0, (size_t)NK * 4, stream);
  hist_k<<<(E + 255) / 256, 256, 0, stream>>>(ei, et, cnt, E);
  scan_partial_k<<<NB, 256, 0, stream>>>(cnt, offs, bsum, NK);
  scan_bsums_k<<<1, 64, 0, stream>>>(bsum, NB);
  scan_addback_k<<<(NK + 255) / 256, 256, 0, stream>>>(offs, bsum, NK, E);
  hipMemsetAsync(cnt, 0, (size_t)NK * 4, stream);
  place_k<<<(E + 255) / 256, 256, 0, stream>>>(ei, et, offs, cnt, pairs, E);

  const int aggBlocks  = (NK + 31) / 32;
  const int gemmBlocks = (N + 127) / 128;
  const int castBlocks = (N * 32 + 255) / 256;

  for (int l = 0; l < 2; ++l) {
    const float* hin = (l == 0) ? x : h1;
    float* opre      = (l == 0) ? h1 : out;

    wcast_k<<<576, 256, 0, stream>>>(weight + (size_t)l * 1024 * 128,
                                     root + (size_t)l * 128 * 128, Whi);
    if (l == 0)
      agg_k<0><<<aggBlocks, 256, 0, stream>>>(hin, xe, xep, pairs, offs, Mb, NK);
    else
      agg_k<1><<<aggBlocks, 256, 0, stream>>>(hin, xe, xep, pairs, offs, Mb, NK);
    if (l == 0)
      cast_swz_k<<<castBlocks, 256, 0, stream>>>(x, hb, N * 32);
    hipMemsetAsync(cst, 0, 256 * 4, stream);
    gemm_k<<<gemmBlocks, 256, 0, stream>>>(Mb, hb, Whi,
                                           bias + (size_t)l * D, opre, cst, N);
    bn_apply_k<<<castBlocks, 256, 0, stream>>>(
        opre, opre, (l == 0) ? hb : (unsigned short*)nullptr,
        cst, gamma + (size_t)l * D, beta + (size_t)l * D, N, (l == 0) ? 1 : 0);
  }
}

// Round 7
// 477.236 us; speedup vs baseline: 1.0400x; 1.0400x over previous
//
#include <hip/hip_runtime.h>
#include <hip/hip_bf16.h>

typedef __attribute__((ext_vector_type(8))) short bf16x8;
typedef __attribute__((ext_vector_type(4))) float f32x4;

constexpr int D = 128;
constexpr int R = 8;
constexpr float BN_EPS = 1e-5f;

__device__ __forceinline__ unsigned short f2bf(float x) {
  __hip_bfloat16 b = __float2bfloat16(x);
  union { __hip_bfloat16 b; unsigned short u; } c; c.b = b; return c.u;
}

// ---------------------------------------------------------------------------
// Counting sort of edges by key = dst*8 + rel (structure shared by both layers)
// ---------------------------------------------------------------------------
__global__ __launch_bounds__(256) void hist_k(const int* __restrict__ ei,
                                              const int* __restrict__ et,
                                              int* __restrict__ cnt, int E) {
  int e = blockIdx.x * 256 + threadIdx.x;
  if (e >= E) return;
  atomicAdd(&cnt[ei[E + e] * 8 + et[e]], 1);
}

__global__ __launch_bounds__(256) void scan_partial_k(const int* __restrict__ cnt,
                                                      int* __restrict__ offs,
                                                      int* __restrict__ bsum, int NK) {
  __shared__ int s[256];
  int tid = threadIdx.x;
  int base = blockIdx.x * 4096 + tid * 16;
  int loc[16];
  int sum = 0;
  #pragma unroll
  for (int i = 0; i < 16; ++i) {
    int idx = base + i;
    int v = (idx < NK) ? cnt[idx] : 0;
    loc[i] = sum; sum += v;
  }
  s[tid] = sum;
  __syncthreads();
  if (tid == 0) {
    int run = 0;
    for (int i = 0; i < 256; ++i) { int t = s[i]; s[i] = run; run += t; }
    bsum[blockIdx.x] = run;
  }
  __syncthreads();
  int off = s[tid];
  #pragma unroll
  for (int i = 0; i < 16; ++i) {
    int idx = base + i;
    if (idx < NK) offs[idx] = off + loc[i];
  }
}

__global__ void scan_bsums_k(int* __restrict__ bsum, int nb) {
  if (threadIdx.x == 0 && blockIdx.x == 0) {
    int run = 0;
    for (int b = 0; b < nb; ++b) { int t = bsum[b]; bsum[b] = run; run += t; }
  }
}

__global__ __launch_bounds__(256) void scan_addback_k(int* __restrict__ offs,
                                                      const int* __restrict__ bsum,
                                                      int NK, int E) {
  int idx = blockIdx.x * 256 + threadIdx.x;
  if (idx < NK) offs[idx] += bsum[idx >> 12];
  if (idx == 0) offs[NK] = E;
}

// place: also pre-gather src so agg has no dependent index chain
__global__ __launch_bounds__(256) void place_k(const int* __restrict__ ei,
                                               const int* __restrict__ et,
                                               const int* __restrict__ offs,
                                               int* __restrict__ cnt,
                                               int2* __restrict__ pairs, int E) {
  int e = blockIdx.x * 256 + threadIdx.x;
  if (e >= E) return;
  int key = ei[E + e] * 8 + et[e];
  int pos = offs[key] + atomicAdd(&cnt[key], 1);
  pairs[pos] = make_int2(e, ei[e]);
}

// ---------------------------------------------------------------------------
// BN prep: colstats -> per-channel scale/shift
// ---------------------------------------------------------------------------
__global__ void bnprep_k(const float* __restrict__ colstats,
                         const float* __restrict__ gamma,
                         const float* __restrict__ beta,
                         float* __restrict__ sc, float* __restrict__ sh, int N) {
  int c = threadIdx.x;   // 128 threads
  float invN = 1.0f / (float)N;
  float mu = colstats[c] * invN;
  float var = colstats[128 + c] * invN - mu * mu;
  float scale = rsqrtf(var + BN_EPS) * gamma[c];
  sc[c] = scale;
  sh[c] = beta[c] - mu * scale;
}

// ---------------------------------------------------------------------------
// Segment mean: each 32-lane group owns FOUR consecutive (dst,rel) segments.
// AFF=1: h input is pre-BN; apply per-channel affine + relu on the gather
//        (folds the previous layer's BN+relu into this kernel).
// rev=1: process segments in reverse perm order (L3 reuse of the xe stream).
// Output: Mb [NK][128] bf16, k-swizzled per 32-channel tile for MFMA frags.
// ---------------------------------------------------------------------------
template <int AFF>
__device__ __forceinline__ void edge_acc(float4& acc, int e, int s, int c,
                                         const float* __restrict__ h,
                                         const float* __restrict__ xe,
                                         const float4 scv, const float4 shv) {
  float4 xv = ((const float4*)xe)[(size_t)e * 32 + c];
  float4 hv = ((const float4*)h)[(size_t)s * 32 + c];
  if (AFF) {
    hv.x = fmaxf(fmaf(hv.x, scv.x, shv.x), 0.f);
    hv.y = fmaxf(fmaf(hv.y, scv.y, shv.y), 0.f);
    hv.z = fmaxf(fmaf(hv.z, scv.z, shv.z), 0.f);
    hv.w = fmaxf(fmaf(hv.w, scv.w, shv.w), 0.f);
  }
  acc.x += fmaxf(xv.x + hv.x, 0.f);
  acc.y += fmaxf(xv.y + hv.y, 0.f);
  acc.z += fmaxf(xv.z + hv.z, 0.f);
  acc.w += fmaxf(xv.w + hv.w, 0.f);
}

template <int AFF>
__global__ __launch_bounds__(256) void agg_k(const float* __restrict__ h,
                                             const float* __restrict__ xe,
                                             const int2* __restrict__ pairs,
                                             const int* __restrict__ offs,
                                             const float* __restrict__ sc,
                                             const float* __restrict__ sh,
                                             unsigned short* __restrict__ Mb,
                                             int NK, int rev) {
  int grp = threadIdx.x >> 5;
  int idx = blockIdx.x * 8 + grp;
  if (idx * 4 >= NK) return;
  if (rev) idx = (NK >> 2) - 1 - idx;
  int s0 = idx * 4;
  int c = threadIdx.x & 31;

  float4 scv = make_float4(0.f, 0.f, 0.f, 0.f), shv = scv;
  if (AFF) {
    scv = *(const float4*)(sc + c * 4);
    shv = *(const float4*)(sh + c * 4);
  }

  int4 ov = *(const int4*)(offs + s0);   // s0 % 4 == 0 -> 16B aligned
  int o4 = offs[s0 + 4];
  int st[4] = {ov.x, ov.y, ov.z, ov.w};
  int en[4] = {ov.y, ov.z, ov.w, o4};

  // issue all 4 pairs loads up front (independent)
  int2 pr[4];
  #pragma unroll
  for (int j = 0; j < 4; ++j) {
    int m = en[j] - st[j];
    if (m > 0) pr[j] = pairs[st[j] + min(c, min(m, 32) - 1)];
  }

  float4 acc[4];
  #pragma unroll
  for (int j = 0; j < 4; ++j) acc[j] = make_float4(0.f, 0.f, 0.f, 0.f);

#define EP(j, i) edge_acc<AFF>(acc[j], __shfl(pr[j].x, (i), 32), \
                               __shfl(pr[j].y, (i), 32), c, h, xe, scv, shv)

  #pragma unroll
  for (int j = 0; j < 4; ++j) {
    int m = en[j] - st[j];
    if (m > 0) {
      int mm = min(m, 32);
      EP(j, 0);
      if (mm >= 2) EP(j, 1);
      if (mm >= 3) EP(j, 2);
      if (mm >= 4) EP(j, 3);
      for (int i = 4; i < mm; ++i) EP(j, i);
      // rare: segments longer than 32
      for (int base = st[j] + 32; base < en[j]; base += 32) {
        int mm2 = min(32, en[j] - base);
        int2 pr2 = pairs[base + min(c, mm2 - 1)];
        for (int i = 0; i < mm2; ++i)
          edge_acc<AFF>(acc[j], __shfl(pr2.x, i, 32), __shfl(pr2.y, i, 32),
                        c, h, xe, scv, shv);
      }
    }
  }
#undef EP

  int pos = (c >> 3) * 32 + (c & 3) * 8 + ((c >> 2) & 1) * 4;
  #pragma unroll
  for (int j = 0; j < 4; ++j) {
    int len = en[j] - st[j];
    float inv = (len > 0) ? 1.0f / (float)len : 0.f;
    ushort4 u;
    u.x = f2bf(acc[j].x * inv); u.y = f2bf(acc[j].y * inv);
    u.z = f2bf(acc[j].z * inv); u.w = f2bf(acc[j].w * inv);
    *(ushort4*)(Mb + (size_t)(s0 + j) * 128 + pos) = u;
  }
}

// cast fp32 [N,128] -> bf16 swizzled [N,128]; AFF: apply affine + relu first
template <int AFF>
__global__ __launch_bounds__(256) void cast_swz_k(const float* __restrict__ in,
                                                  unsigned short* __restrict__ outb,
                                                  const float* __restrict__ sc,
                                                  const float* __restrict__ sh,
                                                  int n4) {
  int gi = blockIdx.x * 256 + threadIdx.x;
  if (gi >= n4) return;
  int n = gi >> 5, c = gi & 31;
  float4 v = ((const float4*)in)[gi];
  if (AFF) {
    float4 scv = *(const float4*)(sc + c * 4);
    float4 shv = *(const float4*)(sh + c * 4);
    v.x = fmaxf(fmaf(v.x, scv.x, shv.x), 0.f);
    v.y = fmaxf(fmaf(v.y, scv.y, shv.y), 0.f);
    v.z = fmaxf(fmaf(v.z, scv.z, shv.z), 0.f);
    v.w = fmaxf(fmaf(v.w, scv.w, shv.w), 0.f);
  }
  int pos = (c >> 3) * 32 + (c & 3) * 8 + ((c >> 2) & 1) * 4;
  ushort4 u;
  u.x = f2bf(v.x); u.y = f2bf(v.y); u.z = f2bf(v.z); u.w = f2bf(v.w);
  *(ushort4*)(outb + (size_t)n * 128 + pos) = u;
}

// W[1152,128] (weight_l | root_l) -> transposed [col][1152], k-swizzled, bf16
__global__ __launch_bounds__(256) void wcast_k(const float* __restrict__ W,
                                               const float* __restrict__ root,
                                               unsigned short* __restrict__ Whi) {
  int idx = blockIdx.x * 256 + threadIdx.x;   // 1152*128 = 147456
  if (idx >= 1152 * 128) return;
  int k = idx >> 7, col = idx & 127;
  float w = (k < 1024) ? W[idx] : root[idx - 1024 * 128];
  int kk = k & 31;
  int pos = (k & ~31) + ((kk & 15) >> 2) * 8 + (kk >> 4) * 4 + (kk & 3);
  Whi[col * 1152 + pos] = f2bf(w);
}

// ---------------------------------------------------------------------------
// MFMA GEMM: out[n,o] = sum_k A[n,k] * W[k,o] + bias[o]
// 256 thr = 4 waves. Block: 128 rows. Wave wv: cols [wv*32, wv*32+32), rf=8.
// A frags direct from global; B frags L1/L2-resident. No LDS in main loop.
// Fused BN column sum/sumsq epilogue.
// ---------------------------------------------------------------------------
__global__ __launch_bounds__(256) void gemm_k(
    const unsigned short* __restrict__ Mb,   // [N,1024] swz
    const unsigned short* __restrict__ hb,   // [N,128] swz
    const unsigned short* __restrict__ Whi,  // [128 cols][1152] swz-k
    const float* __restrict__ bias,
    float* __restrict__ out,
    float* __restrict__ colstats, int N) {
  __shared__ float ldsS[128], ldsQ[128];
  const int tid = threadIdx.x;
  const int wv = tid >> 6, lane = tid & 63;
  const int lr = lane & 15, g = lane >> 4;
  const int r0 = blockIdx.x * 128;
  const int cf0 = wv * 2;

  int row[8];
  #pragma unroll
  for (int rf = 0; rf < 8; ++rf) row[rf] = min(r0 + rf * 16 + lr, N - 1);

  const unsigned short* pb0 = Whi + (size_t)(cf0 * 16 + lr) * 1152 + g * 8;
  const unsigned short* pb1 = pb0 + 16 * 1152;

  f32x4 acc[8][2];
  #pragma unroll
  for (int a = 0; a < 8; ++a)
    #pragma unroll
    for (int b = 0; b < 2; ++b) acc[a][b] = (f32x4){0.f, 0.f, 0.f, 0.f};

  // K over Mb: 32 tiles of 32
  #pragma unroll 2
  for (int t = 0; t < 32; ++t) {
    bf16x8 b0 = *(const bf16x8*)(pb0 + t * 32);
    bf16x8 b1 = *(const bf16x8*)(pb1 + t * 32);
    #pragma unroll
    for (int rf = 0; rf < 8; ++rf) {
      bf16x8 a = *(const bf16x8*)(Mb + (size_t)row[rf] * 1024 + t * 32 + g * 8);
      acc[rf][0] = __builtin_amdgcn_mfma_f32_16x16x32_bf16(a, b0, acc[rf][0], 0, 0, 0);
      acc[rf][1] = __builtin_amdgcn_mfma_f32_16x16x32_bf16(a, b1, acc[rf][1], 0, 0, 0);
    }
  }
  // K over hb: 4 tiles of 32
  #pragma unroll
  for (int tt = 0; tt < 4; ++tt) {
    bf16x8 b0 = *(const bf16x8*)(pb0 + 1024 + tt * 32);
    bf16x8 b1 = *(const bf16x8*)(pb1 + 1024 + tt * 32);
    #pragma unroll
    for (int rf = 0; rf < 8; ++rf) {
      bf16x8 a = *(const bf16x8*)(hb + (size_t)row[rf] * 128 + tt * 32 + g * 8);
      acc[rf][0] = __builtin_amdgcn_mfma_f32_16x16x32_bf16(a, b0, acc[rf][0], 0, 0, 0);
      acc[rf][1] = __builtin_amdgcn_mfma_f32_16x16x32_bf16(a, b1, acc[rf][1], 0, 0, 0);
    }
  }

  // epilogue: bias, store, BN column stats
  #pragma unroll
  for (int c = 0; c < 2; ++c) {
    int col = (cf0 + c) * 16 + lr;
    float bs = bias[col];
    float s = 0.f, q = 0.f;
    #pragma unroll
    for (int rf = 0; rf < 8; ++rf) {
      #pragma unroll
      for (int j = 0; j < 4; ++j) {
        int r = r0 + rf * 16 + g * 4 + j;
        if (r < N) {
          float v = acc[rf][c][j] + bs;
          out[(size_t)r * 128 + col] = v;
          s += v; q += v * v;
        }
      }
    }
    s += __shfl_xor(s, 16); s += __shfl_xor(s, 32);
    q += __shfl_xor(q, 16); q += __shfl_xor(q, 32);
    if (g == 0) { ldsS[col] = s; ldsQ[col] = q; }
  }
  __syncthreads();
  if (tid < 128) {
    atomicAdd(&colstats[tid], ldsS[tid]);
    atomicAdd(&colstats[128 + tid], ldsQ[tid]);
  }
}

// ---------------------------------------------------------------------------
// BN apply (final layer only, no relu)
// ---------------------------------------------------------------------------
__global__ __launch_bounds__(256) void bn_apply_k(
    const float* __restrict__ in, float* __restrict__ out,
    const float* __restrict__ colstats,
    const float* __restrict__ gamma, const float* __restrict__ beta, int N) {
  int gi = blockIdx.x * 256 + threadIdx.x;
  if (gi >= N * 32) return;
  int c0 = (gi & 31) * 4;
  float invN = 1.0f / (float)N;
  float4 v = ((const float4*)in)[gi];
  float4 o;
  #pragma unroll
  for (int j = 0; j < 4; ++j) {
    int cc = c0 + j;
    float mu = colstats[cc] * invN;
    float var = colstats[128 + cc] * invN - mu * mu;
    float scale = rsqrtf(var + BN_EPS) * gamma[cc];
    float shift = beta[cc] - mu * scale;
    float x = (j == 0) ? v.x : (j == 1) ? v.y : (j == 2) ? v.z : v.w;
    float y = x * scale + shift;
    if (j == 0) o.x = y; else if (j == 1) o.y = y; else if (j == 2) o.z = y; else o.w = y;
  }
  ((float4*)out)[gi] = o;
}

extern "C" void kernel_launch(void* const* d_in, const int* in_sizes, int n_in,
                              void* d_out, int out_size, void* d_ws, size_t ws_size,
                              hipStream_t stream) {
  const float* x      = (const float*)d_in[0];
  const float* xe     = (const float*)d_in[1];
  const int*   ei     = (const int*)d_in[2];
  const int*   et     = (const int*)d_in[3];
  const float* weight = (const float*)d_in[4];
  const float* root   = (const float*)d_in[5];
  const float* bias   = (const float*)d_in[6];
  const float* gamma  = (const float*)d_in[7];
  const float* beta   = (const float*)d_in[8];
  float* out = (float*)d_out;

  const int N = in_sizes[0] / D;   // 50000
  const int E = in_sizes[3];       // 500000
  const int NK = N * R;            // 400000

  // workspace layout (256B-aligned chunks)
  char* w = (char*)d_ws;
  size_t off = 0;
  auto alloc = [&](size_t bytes) { char* p = w + off; off = (off + bytes + 255) & ~(size_t)255; return p; };
  unsigned short* Mb   = (unsigned short*)alloc((size_t)NK * 128 * 2);
  unsigned short* hb   = (unsigned short*)alloc((size_t)N * 128 * 2);
  float*          h1   = (float*)alloc((size_t)N * 128 * 4);
  unsigned short* Whi  = (unsigned short*)alloc(1152 * 128 * 2);
  int*            offs = (int*)alloc((size_t)(NK + 1) * 4);
  int*            cnt  = (int*)alloc((size_t)NK * 4);
  int2*           pairs= (int2*)alloc((size_t)E * 8);
  int*            bsum = (int*)alloc(512 * 4);
  float*          cst0 = (float*)alloc(256 * 4);
  float*          cst1 = (float*)alloc(256 * 4);
  float*          sc   = (float*)alloc(128 * 4);
  float*          sh   = (float*)alloc(128 * 4);

  const int NB = (NK + 4095) / 4096;

  // --- counting sort (edge structure; shared by both layers) ---
  hipMemsetAsync(cnt, 0, (size_t)NK * 4, stream);
  hist_k<<<(E + 255) / 256, 256, 0, stream>>>(ei, et, cnt, E);
  scan_partial_k<<<NB, 256, 0, stream>>>(cnt, offs, bsum, NK);
  scan_bsums_k<<<1, 64, 0, stream>>>(bsum, NB);
  scan_addback_k<<<(NK + 255) / 256, 256, 0, stream>>>(offs, bsum, NK, E);
  hipMemsetAsync(cnt, 0, (size_t)NK * 4, stream);
  place_k<<<(E + 255) / 256, 256, 0, stream>>>(ei, et, offs, cnt, pairs, E);

  const int aggBlocks  = (NK + 31) / 32;
  const int gemmBlocks = (N + 127) / 128;
  const int castBlocks = (N * 32 + 255) / 256;

  // ---- layer 0 ----
  wcast_k<<<576, 256, 0, stream>>>(weight, root, Whi);
  agg_k<0><<<aggBlocks, 256, 0, stream>>>(x, xe, pairs, offs, nullptr, nullptr,
                                          Mb, NK, 0);
  cast_swz_k<0><<<castBlocks, 256, 0, stream>>>(x, hb, nullptr, nullptr, N * 32);
  hipMemsetAsync(cst0, 0, 256 * 4, stream);
  gemm_k<<<gemmBlocks, 256, 0, stream>>>(Mb, hb, Whi, bias, h1, cst0, N);
  bnprep_k<<<1, 128, 0, stream>>>(cst0, gamma, beta, sc, sh, N);

  // ---- layer 1 (h1 is pre-BN; BN+relu folded into consumers via sc/sh) ----
  wcast_k<<<576, 256, 0, stream>>>(weight + (size_t)1024 * 128,
                                   root + (size_t)128 * 128, Whi);
  agg_k<1><<<aggBlocks, 256, 0, stream>>>(h1, xe, pairs, offs, sc, sh,
                                          Mb, NK, 1 /*reverse for L3 reuse*/);
  cast_swz_k<1><<<castBlocks, 256, 0, stream>>>(h1, hb, sc, sh, N * 32);
  hipMemsetAsync(cst1, 0, 256 * 4, stream);
  gemm_k<<<gemmBlocks, 256, 0, stream>>>(Mb, hb, Whi, bias + D, out, cst1, N);
  bn_apply_k<<<castBlocks, 256, 0, stream>>>(out, out, cst1, gamma + D, beta + D, N);
}

// Round 8
// 471.020 us; speedup vs baseline: 1.0538x; 1.0132x over previous
//
#include <hip/hip_runtime.h>
#include <hip/hip_bf16.h>

typedef __attribute__((ext_vector_type(8))) short bf16x8;
typedef __attribute__((ext_vector_type(4))) float f32x4;

constexpr int D = 128;
constexpr int R = 8;
constexpr float BN_EPS = 1e-5f;

__device__ __forceinline__ unsigned short f2bf(float x) {
  __hip_bfloat16 b = __float2bfloat16(x);
  union { __hip_bfloat16 b; unsigned short u; } c; c.b = b; return c.u;
}
__device__ __forceinline__ float bf2f(unsigned short u) {
  union { float f; unsigned int i; } c; c.i = ((unsigned int)u) << 16; return c.f;
}

// ---------------------------------------------------------------------------
// Counting sort of edges by key = dst*8 + rel (structure shared by both layers)
// ---------------------------------------------------------------------------
__global__ __launch_bounds__(256) void hist_k(const int* __restrict__ ei,
                                              const int* __restrict__ et,
                                              int* __restrict__ cnt, int E) {
  int e = blockIdx.x * 256 + threadIdx.x;
  if (e >= E) return;
  atomicAdd(&cnt[ei[E + e] * 8 + et[e]], 1);
}

__global__ __launch_bounds__(256) void scan_partial_k(const int* __restrict__ cnt,
                                                      int* __restrict__ offs,
                                                      int* __restrict__ bsum, int NK) {
  __shared__ int s[256];
  int tid = threadIdx.x;
  int base = blockIdx.x * 4096 + tid * 16;
  int loc[16];
  int sum = 0;
  #pragma unroll
  for (int i = 0; i < 16; ++i) {
    int idx = base + i;
    int v = (idx < NK) ? cnt[idx] : 0;
    loc[i] = sum; sum += v;
  }
  s[tid] = sum;
  __syncthreads();
  if (tid == 0) {
    int run = 0;
    for (int i = 0; i < 256; ++i) { int t = s[i]; s[i] = run; run += t; }
    bsum[blockIdx.x] = run;
  }
  __syncthreads();
  int off = s[tid];
  #pragma unroll
  for (int i = 0; i < 16; ++i) {
    int idx = base + i;
    if (idx < NK) offs[idx] = off + loc[i];
  }
}

__global__ void scan_bsums_k(int* __restrict__ bsum, int nb) {
  if (threadIdx.x == 0 && blockIdx.x == 0) {
    int run = 0;
    for (int b = 0; b < nb; ++b) { int t = bsum[b]; bsum[b] = run; run += t; }
  }
}

__global__ __launch_bounds__(256) void scan_addback_k(int* __restrict__ offs,
                                                      const int* __restrict__ bsum,
                                                      int NK, int E) {
  int idx = blockIdx.x * 256 + threadIdx.x;
  if (idx < NK) offs[idx] += bsum[idx >> 12];
  if (idx == 0) offs[NK] = E;
}

// place: also pre-gather src so agg has no dependent index chain
__global__ __launch_bounds__(256) void place_k(const int* __restrict__ ei,
                                               const int* __restrict__ et,
                                               const int* __restrict__ offs,
                                               int* __restrict__ cnt,
                                               int2* __restrict__ pairs, int E) {
  int e = blockIdx.x * 256 + threadIdx.x;
  if (e >= E) return;
  int key = ei[E + e] * 8 + et[e];
  int pos = offs[key] + atomicAdd(&cnt[key], 1);
  pairs[pos] = make_int2(e, ei[e]);
}

// ---------------------------------------------------------------------------
// BN prep: colstats -> per-channel scale/shift
// ---------------------------------------------------------------------------
__global__ void bnprep_k(const float* __restrict__ colstats,
                         const float* __restrict__ gamma,
                         const float* __restrict__ beta,
                         float* __restrict__ sc, float* __restrict__ sh, int N) {
  int c = threadIdx.x;   // 128 threads
  float invN = 1.0f / (float)N;
  float mu = colstats[c] * invN;
  float var = colstats[128 + c] * invN - mu * mu;
  float scale = rsqrtf(var + BN_EPS) * gamma[c];
  sc[c] = scale;
  sh[c] = beta[c] - mu * scale;
}

// ---------------------------------------------------------------------------
// Segment mean: each 32-lane group owns EIGHT consecutive (dst,rel) segments
// (2x the loads-in-flight of the 4-seg version). h is gathered from the
// bf16-swizzled hb (8B/lane; BN+relu pre-applied for layer 1 by cast_swz).
// Output: Mb [NK][128] bf16, k-swizzled per 32-channel tile for MFMA frags.
// ---------------------------------------------------------------------------
__device__ __forceinline__ void edge_acc(float4& acc, int e, int s, int c, int pos,
                                         const unsigned short* __restrict__ hb,
                                         const float* __restrict__ xe) {
  float4 xv = ((const float4*)xe)[(size_t)e * 32 + c];
  ushort4 hu = *(const ushort4*)(hb + (size_t)s * 128 + pos);
  acc.x += fmaxf(xv.x + bf2f(hu.x), 0.f);
  acc.y += fmaxf(xv.y + bf2f(hu.y), 0.f);
  acc.z += fmaxf(xv.z + bf2f(hu.z), 0.f);
  acc.w += fmaxf(xv.w + bf2f(hu.w), 0.f);
}

__global__ __launch_bounds__(256) void agg_k(const unsigned short* __restrict__ hb,
                                             const float* __restrict__ xe,
                                             const int2* __restrict__ pairs,
                                             const int* __restrict__ offs,
                                             unsigned short* __restrict__ Mb,
                                             int NK, int rev) {
  int grp = threadIdx.x >> 5;
  int idx = blockIdx.x * 8 + grp;
  int nIdx = NK >> 3;
  if (idx >= nIdx) return;
  if (rev) idx = nIdx - 1 - idx;
  int s0 = idx * 8;
  int c = threadIdx.x & 31;
  int pos = (c >> 3) * 32 + (c & 3) * 8 + ((c >> 2) & 1) * 4;

  int4 ov0 = *(const int4*)(offs + s0);       // 32B-aligned
  int4 ov1 = *(const int4*)(offs + s0 + 4);
  int o8 = offs[s0 + 8];
  int st[8] = {ov0.x, ov0.y, ov0.z, ov0.w, ov1.x, ov1.y, ov1.z, ov1.w};
  int en[8] = {ov0.y, ov0.z, ov0.w, ov1.x, ov1.y, ov1.z, ov1.w, o8};

  // issue all 8 pairs loads up front (independent)
  int2 pr[8];
  #pragma unroll
  for (int j = 0; j < 8; ++j) {
    int m = en[j] - st[j];
    if (m > 0) pr[j] = pairs[st[j] + min(c, min(m, 32) - 1)];
  }

  float4 acc[8];
  #pragma unroll
  for (int j = 0; j < 8; ++j) acc[j] = make_float4(0.f, 0.f, 0.f, 0.f);

#define EP(j, i) edge_acc(acc[j], __shfl(pr[j].x, (i), 32), \
                          __shfl(pr[j].y, (i), 32), c, pos, hb, xe)

  #pragma unroll
  for (int j = 0; j < 8; ++j) {
    int m = en[j] - st[j];
    if (m > 0) {
      int mm = min(m, 32);
      EP(j, 0);
      if (mm >= 2) EP(j, 1);
      if (mm >= 3) EP(j, 2);
      if (mm >= 4) EP(j, 3);
      for (int i = 4; i < mm; ++i) EP(j, i);
      // rare: segments longer than 32
      for (int base = st[j] + 32; base < en[j]; base += 32) {
        int mm2 = min(32, en[j] - base);
        int2 pr2 = pairs[base + min(c, mm2 - 1)];
        for (int i = 0; i < mm2; ++i)
          edge_acc(acc[j], __shfl(pr2.x, i, 32), __shfl(pr2.y, i, 32),
                   c, pos, hb, xe);
      }
    }
  }
#undef EP

  #pragma unroll
  for (int j = 0; j < 8; ++j) {
    int len = en[j] - st[j];
    float inv = (len > 0) ? 1.0f / (float)len : 0.f;
    ushort4 u;
    u.x = f2bf(acc[j].x * inv); u.y = f2bf(acc[j].y * inv);
    u.z = f2bf(acc[j].z * inv); u.w = f2bf(acc[j].w * inv);
    *(ushort4*)(Mb + (size_t)(s0 + j) * 128 + pos) = u;
  }
}

// cast fp32 [N,128] -> bf16 swizzled [N,128]; AFF: apply affine + relu first
template <int AFF>
__global__ __launch_bounds__(256) void cast_swz_k(const float* __restrict__ in,
                                                  unsigned short* __restrict__ outb,
                                                  const float* __restrict__ sc,
                                                  const float* __restrict__ sh,
                                                  int n4) {
  int gi = blockIdx.x * 256 + threadIdx.x;
  if (gi >= n4) return;
  int n = gi >> 5, c = gi & 31;
  float4 v = ((const float4*)in)[gi];
  if (AFF) {
    float4 scv = *(const float4*)(sc + c * 4);
    float4 shv = *(const float4*)(sh + c * 4);
    v.x = fmaxf(fmaf(v.x, scv.x, shv.x), 0.f);
    v.y = fmaxf(fmaf(v.y, scv.y, shv.y), 0.f);
    v.z = fmaxf(fmaf(v.z, scv.z, shv.z), 0.f);
    v.w = fmaxf(fmaf(v.w, scv.w, shv.w), 0.f);
  }
  int pos = (c >> 3) * 32 + (c & 3) * 8 + ((c >> 2) & 1) * 4;
  ushort4 u;
  u.x = f2bf(v.x); u.y = f2bf(v.y); u.z = f2bf(v.z); u.w = f2bf(v.w);
  *(ushort4*)(outb + (size_t)n * 128 + pos) = u;
}

// W[1152,128] (weight_l | root_l) -> transposed [col][1152], k-swizzled, bf16
__global__ __launch_bounds__(256) void wcast_k(const float* __restrict__ W,
                                               const float* __restrict__ root,
                                               unsigned short* __restrict__ Whi) {
  int idx = blockIdx.x * 256 + threadIdx.x;   // 1152*128 = 147456
  if (idx >= 1152 * 128) return;
  int k = idx >> 7, col = idx & 127;
  float w = (k < 1024) ? W[idx] : root[idx - 1024 * 128];
  int kk = k & 31;
  int pos = (k & ~31) + ((kk & 15) >> 2) * 8 + (kk >> 4) * 4 + (kk & 3);
  Whi[col * 1152 + pos] = f2bf(w);
}

// ---------------------------------------------------------------------------
// MFMA GEMM: out[n,o] = sum_k A[n,k] * W[k,o] + bias[o]
// 256 thr = 4 waves. Block: 128 rows. Wave wv: cols [wv*32, wv*32+32), rf=8.
// A frags direct from global; B frags L1/L2-resident. No LDS in main loop.
// Fused BN column sum/sumsq epilogue.
// ---------------------------------------------------------------------------
__global__ __launch_bounds__(256) void gemm_k(
    const unsigned short* __restrict__ Mb,   // [N,1024] swz
    const unsigned short* __restrict__ hb,   // [N,128] swz
    const unsigned short* __restrict__ Whi,  // [128 cols][1152] swz-k
    const float* __restrict__ bias,
    float* __restrict__ out,
    float* __restrict__ colstats, int N) {
  __shared__ float ldsS[128], ldsQ[128];
  const int tid = threadIdx.x;
  const int wv = tid >> 6, lane = tid & 63;
  const int lr = lane & 15, g = lane >> 4;
  const int r0 = blockIdx.x * 128;
  const int cf0 = wv * 2;

  int row[8];
  #pragma unroll
  for (int rf = 0; rf < 8; ++rf) row[rf] = min(r0 + rf * 16 + lr, N - 1);

  const unsigned short* pb0 = Whi + (size_t)(cf0 * 16 + lr) * 1152 + g * 8;
  const unsigned short* pb1 = pb0 + 16 * 1152;

  f32x4 acc[8][2];
  #pragma unroll
  for (int a = 0; a < 8; ++a)
    #pragma unroll
    for (int b = 0; b < 2; ++b) acc[a][b] = (f32x4){0.f, 0.f, 0.f, 0.f};

  // K over Mb: 32 tiles of 32
  #pragma unroll 2
  for (int t = 0; t < 32; ++t) {
    bf16x8 b0 = *(const bf16x8*)(pb0 + t * 32);
    bf16x8 b1 = *(const bf16x8*)(pb1 + t * 32);
    #pragma unroll
    for (int rf = 0; rf < 8; ++rf) {
      bf16x8 a = *(const bf16x8*)(Mb + (size_t)row[rf] * 1024 + t * 32 + g * 8);
      acc[rf][0] = __builtin_amdgcn_mfma_f32_16x16x32_bf16(a, b0, acc[rf][0], 0, 0, 0);
      acc[rf][1] = __builtin_amdgcn_mfma_f32_16x16x32_bf16(a, b1, acc[rf][1], 0, 0, 0);
    }
  }
  // K over hb: 4 tiles of 32
  #pragma unroll
  for (int tt = 0; tt < 4; ++tt) {
    bf16x8 b0 = *(const bf16x8*)(pb0 + 1024 + tt * 32);
    bf16x8 b1 = *(const bf16x8*)(pb1 + 1024 + tt * 32);
    #pragma unroll
    for (int rf = 0; rf < 8; ++rf) {
      bf16x8 a = *(const bf16x8*)(hb + (size_t)row[rf] * 128 + tt * 32 + g * 8);
      acc[rf][0] = __builtin_amdgcn_mfma_f32_16x16x32_bf16(a, b0, acc[rf][0], 0, 0, 0);
      acc[rf][1] = __builtin_amdgcn_mfma_f32_16x16x32_bf16(a, b1, acc[rf][1], 0, 0, 0);
    }
  }

  // epilogue: bias, store, BN column stats
  #pragma unroll
  for (int c = 0; c < 2; ++c) {
    int col = (cf0 + c) * 16 + lr;
    float bs = bias[col];
    float s = 0.f, q = 0.f;
    #pragma unroll
    for (int rf = 0; rf < 8; ++rf) {
      #pragma unroll
      for (int j = 0; j < 4; ++j) {
        int r = r0 + rf * 16 + g * 4 + j;
        if (r < N) {
          float v = acc[rf][c][j] + bs;
          out[(size_t)r * 128 + col] = v;
          s += v; q += v * v;
        }
      }
    }
    s += __shfl_xor(s, 16); s += __shfl_xor(s, 32);
    q += __shfl_xor(q, 16); q += __shfl_xor(q, 32);
    if (g == 0) { ldsS[col] = s; ldsQ[col] = q; }
  }
  __syncthreads();
  if (tid < 128) {
    atomicAdd(&colstats[tid], ldsS[tid]);
    atomicAdd(&colstats[128 + tid], ldsQ[tid]);
  }
}

// ---------------------------------------------------------------------------
// BN apply (final layer only, no relu)
// ---------------------------------------------------------------------------
__global__ __launch_bounds__(256) void bn_apply_k(
    const float* __restrict__ in, float* __restrict__ out,
    const float* __restrict__ colstats,
    const float* __restrict__ gamma, const float* __restrict__ beta, int N) {
  int gi = blockIdx.x * 256 + threadIdx.x;
  if (gi >= N * 32) return;
  int c0 = (gi & 31) * 4;
  float invN = 1.0f / (float)N;
  float4 v = ((const float4*)in)[gi];
  float4 o;
  #pragma unroll
  for (int j = 0; j < 4; ++j) {
    int cc = c0 + j;
    float mu = colstats[cc] * invN;
    float var = colstats[128 + cc] * invN - mu * mu;
    float scale = rsqrtf(var + BN_EPS) * gamma[cc];
    float shift = beta[cc] - mu * scale;
    float x = (j == 0) ? v.x : (j == 1) ? v.y : (j == 2) ? v.z : v.w;
    float y = x * scale + shift;
    if (j == 0) o.x = y; else if (j == 1) o.y = y; else if (j == 2) o.z = y; else o.w = y;
  }
  ((float4*)out)[gi] = o;
}

extern "C" void kernel_launch(void* const* d_in, const int* in_sizes, int n_in,
                              void* d_out, int out_size, void* d_ws, size_t ws_size,
                              hipStream_t stream) {
  const float* x      = (const float*)d_in[0];
  const float* xe     = (const float*)d_in[1];
  const int*   ei     = (const int*)d_in[2];
  const int*   et     = (const int*)d_in[3];
  const float* weight = (const float*)d_in[4];
  const float* root   = (const float*)d_in[5];
  const float* bias   = (const float*)d_in[6];
  const float* gamma  = (const float*)d_in[7];
  const float* beta   = (const float*)d_in[8];
  float* out = (float*)d_out;

  const int N = in_sizes[0] / D;   // 50000
  const int E = in_sizes[3];       // 500000
  const int NK = N * R;            // 400000

  // workspace layout (256B-aligned chunks)
  char* w = (char*)d_ws;
  size_t off = 0;
  auto alloc = [&](size_t bytes) { char* p = w + off; off = (off + bytes + 255) & ~(size_t)255; return p; };
  unsigned short* Mb   = (unsigned short*)alloc((size_t)NK * 128 * 2);
  unsigned short* hb   = (unsigned short*)alloc((size_t)N * 128 * 2);
  float*          h1   = (float*)alloc((size_t)N * 128 * 4);
  unsigned short* Whi  = (unsigned short*)alloc(1152 * 128 * 2);
  int*            offs = (int*)alloc((size_t)(NK + 8) * 4);
  int*            cnt  = (int*)alloc((size_t)NK * 4);
  int2*           pairs= (int2*)alloc((size_t)E * 8);
  int*            bsum = (int*)alloc(512 * 4);
  float*          cst0 = (float*)alloc(256 * 4);
  float*          cst1 = (float*)alloc(256 * 4);
  float*          sc   = (float*)alloc(128 * 4);
  float*          sh   = (float*)alloc(128 * 4);

  const int NB = (NK + 4095) / 4096;

  // --- counting sort (edge structure; shared by both layers) ---
  hipMemsetAsync(cnt, 0, (size_t)NK * 4, stream);
  hist_k<<<(E + 255) / 256, 256, 0, stream>>>(ei, et, cnt, E);
  scan_partial_k<<<NB, 256, 0, stream>>>(cnt, offs, bsum, NK);
  scan_bsums_k<<<1, 64, 0, stream>>>(bsum, NB);
  scan_addback_k<<<(NK + 255) / 256, 256, 0, stream>>>(offs, bsum, NK, E);
  hipMemsetAsync(cnt, 0, (size_t)NK * 4, stream);
  place_k<<<(E + 255) / 256, 256, 0, stream>>>(ei, et, offs, cnt, pairs, E);

  const int aggBlocks  = ((NK >> 3) + 7) / 8;
  const int gemmBlocks = (N + 127) / 128;
  const int castBlocks = (N * 32 + 255) / 256;

  // ---- layer 0 ----
  wcast_k<<<576, 256, 0, stream>>>(weight, root, Whi);
  cast_swz_k<0><<<castBlocks, 256, 0, stream>>>(x, hb, nullptr, nullptr, N * 32);
  agg_k<<<aggBlocks, 256, 0, stream>>>(hb, xe, pairs, offs, Mb, NK, 0);
  hipMemsetAsync(cst0, 0, 256 * 4, stream);
  gemm_k<<<gemmBlocks, 256, 0, stream>>>(Mb, hb, Whi, bias, h1, cst0, N);
  bnprep_k<<<1, 128, 0, stream>>>(cst0, gamma, beta, sc, sh, N);

  // ---- layer 1 (h1 is pre-BN; BN+relu folded into cast_swz via sc/sh) ----
  wcast_k<<<576, 256, 0, stream>>>(weight + (size_t)1024 * 128,
                                   root + (size_t)128 * 128, Whi);
  cast_swz_k<1><<<castBlocks, 256, 0, stream>>>(h1, hb, sc, sh, N * 32);
  agg_k<<<aggBlocks, 256, 0, stream>>>(hb, xe, pairs, offs, Mb, NK, 1);
  hipMemsetAsync(cst1, 0, 256 * 4, stream);
  gemm_k<<<gemmBlocks, 256, 0, stream>>>(Mb, hb, Whi, bias + D, out, cst1, N);
  bn_apply_k<<<castBlocks, 256, 0, stream>>>(out, out, cst1, gamma + D, beta + D, N);
}